// Round 5
// baseline (276.501 us; speedup 1.0000x reference)
//
#include <hip/hip_runtime.h>
#include <hip/hip_bf16.h>
#include <math.h>

// Problem constants (from reference):
//   B=16, H=W=512, HS=WS=54, WIN=4 -> PW=PH=51, CROP=64, RF=70
//   stride = floor((512-70)/54) = 8
#define BB   16
#define HH   512
#define WW   512
#define HS   54
#define WS_  54
#define PH_  51
#define CROP 64

// ---------------------------------------------------------------------------
// Kernel 1: per-batch argmax over score_map[b,0,:51,:51]; writes ax (float x2)
// ---------------------------------------------------------------------------
__global__ void localize_kernel(const float* __restrict__ score,
                                float* __restrict__ ws_ax) {
    const int b = blockIdx.x;
    const float* m = score + (size_t)b * HS * WS_;

    float bv = -INFINITY;
    int   bi = 0x7fffffff;
    for (int i = threadIdx.x; i < PH_ * PH_; i += blockDim.x) {
        int r = i / PH_;
        int c = i - r * PH_;
        float v = m[r * WS_ + c];
        // first-occurrence tie-break like jnp.argmax
        if (v > bv || (v == bv && i < bi)) { bv = v; bi = i; }
    }

    __shared__ float sv[256];
    __shared__ int   si[256];
    sv[threadIdx.x] = bv;
    si[threadIdx.x] = bi;
    __syncthreads();
    for (int s = 128; s > 0; s >>= 1) {
        if ((int)threadIdx.x < s) {
            float ov = sv[threadIdx.x + s];
            int   oi = si[threadIdx.x + s];
            if (ov > sv[threadIdx.x] ||
                (ov == sv[threadIdx.x] && oi < si[threadIdx.x])) {
                sv[threadIdx.x] = ov;
                si[threadIdx.x] = oi;
            }
        }
        __syncthreads();
    }

    if (threadIdx.x == 0) {
        float best = sv[0];
        int   idx  = si[0];
        int x = (best > 0.0f) ? (idx / PH_) : 0;
        int y = (best > 0.0f) ? (idx % PH_) : 0;
        float stride = floorf((512.0f - 70.0f) / 54.0f);  // 8.0
        ws_ax[2 * b]     = (float)x * stride + 70.0f;     // ax[:,0] (H index)
        ws_ax[2 * b + 1] = (float)y * stride + 70.0f;     // ax[:,1] (W index)
    }
}

// ---------------------------------------------------------------------------
// Kernel 2: bulk copy real_AB -> out[0 : 16*6*512*512]  (float4, grid-stride)
// ---------------------------------------------------------------------------
__global__ void copy_kernel(const float4* __restrict__ src,
                            float4* __restrict__ dst, int n4) {
    int i = blockIdx.x * blockDim.x + threadIdx.x;
    int gstride = gridDim.x * blockDim.x;
    for (; i < n4; i += gstride) dst[i] = src[i];
}

// ---------------------------------------------------------------------------
// Kernel 3: overwrite the 96 substituted elements out[b,c,xi,yi] = fake_AB[...]
// ---------------------------------------------------------------------------
__global__ void fixup_kernel(const float* __restrict__ fake_AB,
                             const float* __restrict__ ws_ax,
                             float* __restrict__ out) {
    int t = threadIdx.x;
    if (t >= BB * 6) return;
    int b = t / 6;
    int c = t - b * 6;
    int xi = (int)ws_ax[2 * b];
    int yi = (int)ws_ax[2 * b + 1];
    size_t off = ((((size_t)b * 6 + c) * HH) + xi) * WW + yi;
    out[off] = fake_AB[off];
}

// ---------------------------------------------------------------------------
// Kernel 4: crops. One thread per output pixel of real_Br / fake_Br.
// Replicates reference float32 arithmetic exactly (no FMA contraction so the
// vy/vx boundary decisions match XLA's elementwise ops).
// ---------------------------------------------------------------------------
__global__ void crop_kernel(const float* __restrict__ real_B,
                            const float* __restrict__ fake_B,
                            const float* __restrict__ ws_ax,
                            float* __restrict__ out) {
#pragma clang fp contract(off)
    const int PER_IMG = BB * 3 * CROP * CROP;  // 196608
    int idx = blockIdx.x * blockDim.x + threadIdx.x;
    if (idx >= 2 * PER_IMG) return;

    int which = idx >= PER_IMG ? 1 : 0;       // 0 = real_Br, 1 = fake_Br
    int j = idx - which * PER_IMG;
    int b   = j / (3 * CROP * CROP);
    int rem = j - b * (3 * CROP * CROP);
    int c   = rem >> 12;                       // / (64*64)
    int pix = rem & 4095;
    int ry  = pix >> 6;
    int rx  = pix & 63;

    // _boxes, replicated
    float y1 = ws_ax[2 * b];       // ax[:,0]
    float x1 = ws_ax[2 * b + 1];   // ax[:,1]
    float x2 = x1 + (float)CROP;
    float y2 = y1 + (float)CROP;
    float sw = (x2 - x1) / (float)CROP;
    float sh = (y2 - y1) / (float)CROP;
    float nx0 = (x1 + sw / 2.0f - 0.5f) / (float)(WW - 1);
    float ny0 = (y1 + sh / 2.0f - 0.5f) / (float)(HH - 1);
    float nw = sw * (float)(CROP - 1) / (float)(WW - 1);
    float nh = sh * (float)(CROP - 1) / (float)(HH - 1);
    float ny1 = ny0 + nh;
    float nx1 = nx0 + nw;

    // _crop_and_resize, replicated
    float ys = ny0 * (float)(HH - 1) +
               (float)ry * (ny1 - ny0) * (float)(HH - 1) / (float)(CROP - 1);
    float xs = nx0 * (float)(WW - 1) +
               (float)rx * (nx1 - nx0) * (float)(WW - 1) / (float)(CROP - 1);
    bool vy = (ys >= 0.0f) && (ys <= (float)(HH - 1));
    bool vx = (xs >= 0.0f) && (xs <= (float)(WW - 1));

    float y0f = floorf(ys);
    float x0f = floorf(xs);
    int y0 = (int)fminf(fmaxf(y0f, 0.0f), (float)(HH - 1));
    int x0 = (int)fminf(fmaxf(x0f, 0.0f), (float)(WW - 1));
    int y1i = min(y0 + 1, HH - 1);
    int x1i = min(x0 + 1, WW - 1);
    float ly = ys - y0f;
    float lx = xs - x0f;

    const float* src = which ? fake_B : real_B;
    const float* img = src + (((size_t)b * 3 + c) * HH) * WW;

    float v00 = img[(size_t)y0 * WW + x0];
    float v01 = img[(size_t)y0 * WW + x1i];
    float v10 = img[(size_t)y1i * WW + x0];
    float v11 = img[(size_t)y1i * WW + x1i];

    float top = (1.0f - lx) * v00 + lx * v01;
    float bot = (1.0f - lx) * v10 + lx * v11;
    float o   = (1.0f - ly) * top + ly * bot;
    o = (vy && vx) ? o : 0.0f;

    const size_t OUT_AB = (size_t)BB * 6 * HH * WW;  // 25165824
    out[OUT_AB + (size_t)which * PER_IMG + (size_t)j] = o;
}

// ---------------------------------------------------------------------------
extern "C" void kernel_launch(void* const* d_in, const int* in_sizes, int n_in,
                              void* d_out, int out_size, void* d_ws, size_t ws_size,
                              hipStream_t stream) {
    const float* real_AB   = (const float*)d_in[0];
    const float* fake_AB   = (const float*)d_in[1];
    const float* score_map = (const float*)d_in[2];
    const float* real_B    = (const float*)d_in[3];
    const float* fake_B    = (const float*)d_in[4];
    float* out = (float*)d_out;
    float* ws_ax = (float*)d_ws;  // 32 floats

    // Big copy first (independent of localize), then localize, fixup, crops.
    const int n4 = (BB * 6 * HH * WW) / 4;  // 6291456 float4s
    copy_kernel<<<4096, 256, 0, stream>>>((const float4*)real_AB,
                                          (float4*)out, n4);

    localize_kernel<<<BB, 256, 0, stream>>>(score_map, ws_ax);

    fixup_kernel<<<1, 128, 0, stream>>>(fake_AB, ws_ax, out);

    const int total = 2 * BB * 3 * CROP * CROP;  // 786432
    crop_kernel<<<(total + 255) / 256, 256, 0, stream>>>(real_B, fake_B,
                                                         ws_ax, out);
}